// Round 5
// baseline (3019.831 us; speedup 1.0000x reference)
//
#include <hip/hip_runtime.h>

#define HID     1024
#define TSTEPS  19
#define INDIM   17
#define XSTRIDE (TSTEPS * INDIM)

typedef unsigned short u16;
typedef unsigned int   u32;
typedef __attribute__((ext_vector_type(8))) _Float16 f16x8;  // 8 fp16 = 4 VGPRs
typedef __attribute__((ext_vector_type(4))) float f32x4;

__device__ __forceinline__ u16 f2h(float f) {  // fp32 -> fp16 RNE
    union { _Float16 h; u16 u; } v; v.h = (_Float16)f; return v.u;
}
__device__ __forceinline__ float h2f(u16 x) {
    union { _Float16 h; u16 u; } v; v.u = x; return (float)v.h;
}
__device__ __forceinline__ float sigm(float x) {
    x = fminf(fmaxf(x, -30.f), 30.f);
    return 1.f / (1.f + __expf(-x));
}
__device__ __forceinline__ float tanhr(float x) {
    x = fminf(fmaxf(x, -15.f), 15.f);
    float e = __expf(-2.f * x);
    return (1.f - e) / (1.f + e);
}

// Async global->LDS, 16B per lane: HW writes wave-uniform LDS base + lane*16.
__device__ __forceinline__ void gload_lds16(const u16* g, u16* l) {
    __builtin_amdgcn_global_load_lds(
        (const __attribute__((address_space(1))) u32*)g,
        (__attribute__((address_space(3))) u32*)l, 16, 0, 0);
}

// Fused prolog split: fp32 -> fp16 hi for the three big weights + W_lin.
#define NW4 1048576   // float4s per 4H x H weight
__global__ __launch_bounds__(256) void split4_kernel(
    const float* __restrict__ a, u16* __restrict__ ah,
    const float* __restrict__ b, u16* __restrict__ bh,
    const float* __restrict__ c, u16* __restrict__ ch,
    const float* __restrict__ d, u16* __restrict__ dh, int nd4)
{
    int i = blockIdx.x * blockDim.x + threadIdx.x;
    const float* src; u16* dst; int off;
    if (i < NW4)               { src = a; dst = ah; off = i; }
    else if (i < 2 * NW4)      { src = b; dst = bh; off = i - NW4; }
    else if (i < 3 * NW4)      { src = c; dst = ch; off = i - 2 * NW4; }
    else if (i < 3 * NW4 + nd4){ src = d; dst = dh; off = i - 3 * NW4; }
    else return;
    float4 v = ((const float4*)src)[off];
    ushort4 h;
    h.x = f2h(v.x); h.y = f2h(v.y); h.z = f2h(v.z); h.w = f2h(v.w);
    ((ushort4*)dst)[off] = h;
}

// Pre-pack x into standard BK=64 GEMM rows: xpack[(t*4096+b)*64 + k] =
// [xhi(17) | xlo(17) | xhi(17) | 0...] -- the 3-term fp16 split of x[b,t,:]
// as one K=64 stage.
__global__ __launch_bounds__(256) void pack_x_kernel(
    const float* __restrict__ x, u16* __restrict__ xpack)
{
    const int i = blockIdx.x * blockDim.x + threadIdx.x;  // i = t*4096 + b
    if (i >= TSTEPS * 4096) return;
    const int t = i >> 12, b = i & 4095;
    const float* src = x + (size_t)b * XSTRIDE + (size_t)t * INDIM;
    u16 row[64];
#pragma unroll
    for (int k = 0; k < INDIM; ++k) {
        const float v = src[k];
        const u16 hi = f2h(v);
        row[k] = hi;
        row[INDIM + k] = f2h(v - h2f(hi));   // lo
        row[2 * INDIM + k] = hi;
    }
#pragma unroll
    for (int k = 3 * INDIM; k < 64; ++k) row[k] = 0;
    uint4* dst = (uint4*)(xpack + (size_t)i * 64);
#pragma unroll
    for (int q = 0; q < 8; ++q) dst[q] = ((const uint4*)row)[q];
}

// Pre-pack W_ih1 rows to match: wxpack[n*64 + k] = [Whi | Whi | Wlo | 0].
__global__ __launch_bounds__(256) void pack_wx_kernel(
    const float* __restrict__ W, u16* __restrict__ wxpack)
{
    const int n = blockIdx.x * blockDim.x + threadIdx.x;
    if (n >= 4 * HID) return;
    const float* src = W + (size_t)n * INDIM;
    u16 row[64];
#pragma unroll
    for (int k = 0; k < INDIM; ++k) {
        const float v = src[k];
        const u16 hi = f2h(v);
        row[k] = hi;
        row[INDIM + k] = hi;
        row[2 * INDIM + k] = f2h(v - h2f(hi));  // lo
    }
#pragma unroll
    for (int k = 3 * INDIM; k < 64; ++k) row[k] = 0;
    uint4* dst = (uint4*)(wxpack + (size_t)n * 64);
#pragma unroll
    for (int q = 0; q < 8; ++q) dst[q] = ((const uint4*)row)[q];
}

// Fused GEMM + LSTM cell body -- 256x128 tile, 4 waves.
// r18 = r14's VERIFIED sync structure (2x __syncthreads/stage, 16x16x32
// MFMA, 0-bank-conflict B read pattern) with the A-LDS DETOUR REMOVED:
// the A-tile has ZERO LDS reuse (each wave reads only its own staged
// slab, each byte exactly once), so A fragments now load DIRECTLY
// global->VGPR. Fragment address: lane(quad,col) reads
// A[row = rf*16+col][k0 + (ks*4+quad)*8 ..+7] -- the 4 quads fetch 4
// consecutive 16B chunks = coalesced 64B half-lines (16 lines/instr),
// and ks=0/ks=1 hit the two halves of the same 128B row-line.
// Effects: LDS traffic per stage/CU 288->160KB (was the critical pipe,
// ~1125cy vs MFMA's ~620cy); barrier vmcnt-drain queue 12->4 gloads;
// LDS 48->16KB. Register-neutral: av[4] are the load destinations
// (same 16 VGPRs r14 used for the LDS-read results).
// r17's lessons kept: exact-write epilogue (s2-inner, both 64B halves
// of each c-line stored back-to-back: WRITE_SIZE 64.5->49.5MB).
// r17's 32x32 shape dropped: +9.6M bank conflicts (4 cy/read, uniform).
__device__ __forceinline__ void gate_body(
    u16* lB, int rb, int u0,
    const u16* __restrict__ a0, const u16* __restrict__ w0,
    const u16* __restrict__ a1, const u16* __restrict__ w1,
    const u16* __restrict__ xp, const u16* __restrict__ wxp,
    const float* __restrict__ bi, const float* __restrict__ bh,
    float* __restrict__ cbuf, u16* __restrict__ outh,
    int first, int nsrc)
{
    const int tid  = threadIdx.x;
    const int wave = tid >> 6;    // 0..3
    const int lane = tid & 63;
    const int col  = lane & 15;   // MFMA A/B m|n index; C/D col
    const int quad = lane >> 4;   // MFMA k-group; C/D row group

    const int lr = lane >> 3;         // B-staging row-in-group-of-8
    const int ck = (lane & 7) ^ lr;   // xor-swizzled global chunk to fetch

    f32x4 acc[4][8];
    const f32x4 fzero = {0.f, 0.f, 0.f, 0.f};
#pragma unroll
    for (int i = 0; i < 4; ++i)
#pragma unroll
        for (int j = 0; j < 8; ++j) acc[i][j] = fzero;

    const int nst = nsrc << 4;                  // 16 stages per stride-HID pair
    const int ntot = nst + (xp ? 1 : 0);        // + one packed x stage
    for (int s = 0; s < ntot; ++s) {
        const bool isx = (s >= nst);
        const u16* Asrc = isx ? xp  : ((s < 16) ? a0 : a1);
        const u16* Wsrc = isx ? wxp : ((s < 16) ? w0 : w1);
        const int k0 = isx ? 0 : (s & 15) * 64;
        const int st = isx ? 64 : HID;          // row stride (elements)

        __syncthreads();  // previous stage's lB reads done
#pragma unroll
        for (int i = 0; i < 4; ++i) {   // B: this wave's quarter of 128 rows
            const int vbase = wave * 32 + i * 8;
            const int v = vbase + lr;
            const int n = ((v >> 5) << 10) + u0 + (v & 31);  // gate*1024 + u
            const u16* gp = Wsrc + (size_t)n * st + k0 + ck * 8;
            gload_lds16(gp, lB + vbase * 64);
        }
        __syncthreads();  // staging visible (barrier drains vmcnt)

#pragma unroll
        for (int ks = 0; ks < 2; ++ks) {
            // A fragments: DIRECT global loads (logical chunk ks*4+quad,
            // no xor -- the swizzle was an LDS-bank artifact).
            const u16* abase = Asrc + (size_t)(rb + wave * 64 + col) * st
                             + k0 + (ks * 4 + quad) * 8;
            f16x8 av[4], bv[8];
#pragma unroll
            for (int rf = 0; rf < 4; ++rf)
                av[rf] = *(const f16x8*)(abase + (size_t)rf * 16 * st);
            const int p = ((ks << 2) + quad) ^ (col & 7);  // swizzled chunk
#pragma unroll
            for (int cf = 0; cf < 8; ++cf)
                bv[cf] = *(const f16x8*)(lB + (cf * 16 + col) * 64 + p * 8);
#pragma unroll
            for (int rf = 0; rf < 4; ++rf)
#pragma unroll
                for (int cf = 0; cf < 8; ++cf)
                    acc[rf][cf] = __builtin_amdgcn_mfma_f32_16x16x32_f16(
                        av[rf], bv[cf], acc[rf][cf], 0, 0, 0);
        }
    }

    // Epilogue: per-lane LSTM cell. C/D layout: col=lane&15, row=quad*4+reg.
    // Gates of unit u = u0 + s2*16 + col live at cf = {s2, 2+s2, 4+s2, 6+s2}.
    // s2-INNER so the two 64B halves of each 128B c-line (and the two 32B
    // halves of each 64B h chunk) store back-to-back -> full-line writeback
    // (r17 evidence: exact WRITE_SIZE vs +15MB partial-line RMW).
    const int u_a = u0 + col;         // s2 = 0
    const int u_b = u0 + 16 + col;    // s2 = 1
    const float bIa = bi[u_a]           + bh[u_a];
    const float bFa = bi[HID + u_a]     + bh[HID + u_a];
    const float bGa = bi[2 * HID + u_a] + bh[2 * HID + u_a];
    const float bOa = bi[3 * HID + u_a] + bh[3 * HID + u_a];
    const float bIb = bi[u_b]           + bh[u_b];
    const float bFb = bi[HID + u_b]     + bh[HID + u_b];
    const float bGb = bi[2 * HID + u_b] + bh[2 * HID + u_b];
    const float bOb = bi[3 * HID + u_b] + bh[3 * HID + u_b];
#pragma unroll
    for (int rf = 0; rf < 4; ++rf) {
#pragma unroll
        for (int rr = 0; rr < 4; ++rr) {
            const int brow = rb + wave * 64 + rf * 16 + quad * 4 + rr;
            const size_t idx0 = (size_t)brow * HID + u_a;
            const size_t idx1 = idx0 + 16;
            const float iva = sigm(acc[rf][0][rr] + bIa);
            const float fva = sigm(acc[rf][2][rr] + bFa);
            const float gva = tanhr(acc[rf][4][rr] + bGa);
            const float ova = sigm(acc[rf][6][rr] + bOa);
            const float ivb = sigm(acc[rf][1][rr] + bIb);
            const float fvb = sigm(acc[rf][3][rr] + bFb);
            const float gvb = tanhr(acc[rf][5][rr] + bGb);
            const float ovb = sigm(acc[rf][7][rr] + bOb);
            const float colda = first ? 0.f : cbuf[idx0];
            const float coldb = first ? 0.f : cbuf[idx1];
            const float cna = fva * colda + iva * gva;
            const float cnb = fvb * coldb + ivb * gvb;
            const float hna = ova * tanhr(cna);
            const float hnb = ovb * tanhr(cnb);
            cbuf[idx0] = cna;
            cbuf[idx1] = cnb;
            outh[idx0] = f2h(hna);
            outh[idx1] = f2h(hnb);
        }
    }
}

// out[b, t, :] = h2[b,:] @ W_lin^T + b_lin (h2 fp16, W_lin pre-split fp16).
__device__ __forceinline__ void out_body8(int oid,
    const u16* __restrict__ h2h,
    const u16* __restrict__ Wlin, const float* __restrict__ blin,
    float* __restrict__ out, int t)
{
    const int tid = threadIdx.x;
    const int wave = tid >> 6, lane = tid & 63;
    const int r = lane >> 5, q = lane & 31;
    const int b = oid * 8 + wave * 2 + r;
    const u16* hh = h2h + (size_t)b * HID;
    float acc[INDIM];
#pragma unroll
    for (int j = 0; j < INDIM; ++j) acc[j] = 0.f;
#pragma unroll 2
    for (int it = 0; it < 8; ++it) {
        const int u = q * 32 + it * 4;
        const ushort4 a = *(const ushort4*)(hh + u);
        const float h0 = h2f(a.x), h1 = h2f(a.y), h2 = h2f(a.z), h3 = h2f(a.w);
#pragma unroll
        for (int j = 0; j < INDIM; ++j) {
            const ushort4 w = *(const ushort4*)(Wlin + j * HID + u);
            acc[j] += h0 * h2f(w.x) + h1 * h2f(w.y)
                    + h2 * h2f(w.z) + h3 * h2f(w.w);
        }
    }
#pragma unroll
    for (int j = 0; j < INDIM; ++j) {   // reduce across the 32 q-slices
        float v = acc[j];
        v += __shfl_xor(v, 1);
        v += __shfl_xor(v, 2);
        v += __shfl_xor(v, 4);
        v += __shfl_xor(v, 8);
        v += __shfl_xor(v, 16);
        acc[j] = v;
    }
    const size_t ob = (size_t)b * XSTRIDE + (size_t)t * INDIM;
    float mine = acc[0];
#pragma unroll
    for (int j = 1; j < INDIM; ++j) if (q == j) mine = acc[j];
    if (q < INDIM) out[ob + q] = mine + blin[q];
}

// Fused pipeline step C(s) = { L2(s-1) + L1(s) + OUT(s-2) }, grid EXACTLY
// 512 blocks x 256 thr (2 blocks/CU; LDS now only 16KB, occupancy is
// register-capped at 2 blocks). Role-order STAGGER by block parity (r14,
// +2%): a CU's two resident blocks are mostly in different roles; MFMA
// windows overlap the neighbor's staging/barrier drains (m114).
// XCD-pinned u0 (perf heuristic only). Buffer schedule = verified 4-deep
// slab rotation (r8-r14).
__global__ __launch_bounds__(256, 2) void step_kernel(
    int doA, int doB,
    // role A: layer 2 of step s-1
    const u16* __restrict__ Aa0, const u16* __restrict__ Aw0,
    const u16* __restrict__ Aa1, const u16* __restrict__ Aw1,
    const float* __restrict__ Abi, const float* __restrict__ Abh,
    float* __restrict__ Acbuf, u16* __restrict__ Aouth, int Afirst, int Ansrc,
    // role B: layer 1 of step s (x via pre-packed stride-64 pair)
    const u16* __restrict__ Ba0, const u16* __restrict__ Bw0,
    const u16* __restrict__ Bxp, const u16* __restrict__ Bwxp,
    const float* __restrict__ Bbi, const float* __restrict__ Bbh,
    float* __restrict__ Bcbuf, u16* __restrict__ Bouth, int Bfirst, int Bnsrc,
    // role O: output linear of step s-2 (Ot < 0 => skip)
    const u16* __restrict__ Oh2, const u16* __restrict__ Wlin,
    const float* __restrict__ blin, float* __restrict__ outp, int Ot)
{
    __shared__ u16 lB[128 * 64];   // 16 KB: 128 weight rows x BK=64
    const int bid = blockIdx.x;
    const int rb  = (bid >> 5) * 256;                        // batch-row block
    const int u0  = ((bid & 7) * 4 + ((bid >> 3) & 3)) * 32; // XCD-pinned tile
    const auto runA = [&]() {
        gate_body(lB, rb, u0, Aa0, Aw0, Aa1, Aw1, nullptr, nullptr,
                  Abi, Abh, Acbuf, Aouth, Afirst, Ansrc);
    };
    const auto runB = [&]() {
        gate_body(lB, rb, u0, Ba0, Bw0, nullptr, nullptr, Bxp, Bwxp,
                  Bbi, Bbh, Bcbuf, Bouth, Bfirst, Bnsrc);
    };
    if (bid & 1) { if (doB) runB(); if (doA) runA(); }
    else         { if (doA) runA(); if (doB) runB(); }
    if (Ot >= 0)
        out_body8(bid, Oh2, Wlin, blin, outp, Ot);
}

extern "C" void kernel_launch(void* const* d_in, const int* in_sizes, int n_in,
                              void* d_out, int out_size, void* d_ws, size_t ws_size,
                              hipStream_t stream)
{
    const float* x     = (const float*)d_in[0];
    const float* W_ih1 = (const float*)d_in[1];
    const float* W_hh1 = (const float*)d_in[2];
    const float* b_ih1 = (const float*)d_in[3];
    const float* b_hh1 = (const float*)d_in[4];
    const float* W_ih2 = (const float*)d_in[5];
    const float* W_hh2 = (const float*)d_in[6];
    const float* b_ih2 = (const float*)d_in[7];
    const float* b_hh2 = (const float*)d_in[8];
    const float* W_lin = (const float*)d_in[9];
    const float* b_lin = (const float*)d_in[10];
    float* out = (float*)d_out;
    char* ws = (char*)d_ws;
    const size_t MB = (size_t)1 << 20;

    // Workspace (~132 MB; no memset -- first=1 skips all reads of
    // uninitialized state at t=0). c1/c2 fp32; h1/h2: FOUR 8MB fp16 slabs
    // each (t&3); wlin16 = fp16 W_lin for the O-body.
    float* c1 = (float*)(ws);             // 16 MB (4096x1024 fp32)
    float* c2 = (float*)(ws + 16 * MB);   // 16 MB
    u16* h1[4] = { (u16*)(ws + 32 * MB), (u16*)(ws + 40 * MB),
                   (u16*)(ws + 48 * MB), (u16*)(ws + 56 * MB) };
    u16* h2[4] = { (u16*)(ws + 64 * MB), (u16*)(ws + 72 * MB),
                   (u16*)(ws + 80 * MB), (u16*)(ws + 88 * MB) };
    u16* w1h    = (u16*)(ws + 96 * MB);   // 8 MB each (4H x H fp16)
    u16* w2ih   = (u16*)(ws + 104 * MB);
    u16* w2hh   = (u16*)(ws + 112 * MB);
    u16* xpack  = (u16*)(ws + 120 * MB);  // 19*4096*64 fp16 = 9.97 MB
    u16* wxpack = (u16*)(ws + 130 * MB);  // 4096*64 fp16 = 0.5 MB
    u16* wlin16 = (u16*)(ws + 131 * MB);  // 17*1024 fp16 = 34 KB

    // Prolog (3 launches): fused weight+W_lin fp16 splits, x / W_ih1 packs.
    const int nWlin4 = INDIM * HID / 4;   // 4352 float4s
    const int nTot = 3 * NW4 + nWlin4;
    split4_kernel<<<(nTot + 255) / 256, 256, 0, stream>>>(
        W_hh1, w1h, W_ih2, w2ih, W_hh2, w2hh, W_lin, wlin16, nWlin4);
    pack_x_kernel<<<(TSTEPS * 4096 + 255) / 256, 256, 0, stream>>>(x, xpack);
    pack_wx_kernel<<<(4 * HID + 255) / 256, 256, 0, stream>>>(W_ih1, wxpack);

    // Software pipeline: C(s) = { L2(s-1) + L1(s) + OUT(s-2) }, s=0..TSTEPS+1.
    // Slabs: L1(t) reads h1[(t+3)&3], writes h1[t&3]; L2(t) reads h1[t&3],
    // h2[(t+3)&3], writes h2[t&3]; OUT(t) reads h2[t&3]. Intra-launch sets
    // disjoint; RAW >= 1 launch, WAR >= 3 launches (verified r8-r14).
    for (int s = 0; s <= TSTEPS + 1; ++s) {
        const int ta = s - 1, tb = s, to = s - 2;
        const int doA = (s >= 1 && s <= TSTEPS) ? 1 : 0;
        const int doB = (s <= TSTEPS - 1) ? 1 : 0;
        step_kernel<<<512, 256, 0, stream>>>(
            doA, doB,
            // A: L2(ta) = h1[ta&3]@w2ih + h2[(ta+3)&3]@w2hh -> h2[ta&3]
            h1[ta & 3], w2ih, h2[(ta + 3) & 3], w2hh, b_ih2, b_hh2,
            c2, h2[ta & 3], (ta == 0) ? 1 : 0, (ta == 0) ? 1 : 2,
            // B: L1(tb) = xpack(tb) + h1[(tb+3)&3]@w1h -> h1[tb&3]
            h1[(tb + 3) & 3], w1h,
            xpack + (size_t)(tb < 0 ? 0 : tb) * 4096 * 64, wxpack,
            b_ih1, b_hh1,
            c1, h1[tb & 3], (tb == 0) ? 1 : 0, (tb == 0) ? 0 : 1,
            // O: OUT(to) reads h2[to&3] (skipped when to < 0)
            h2[to & 3], wlin16, b_lin, out, to);
    }
    (void)in_sizes; (void)n_in; (void)out_size; (void)ws_size;
}

// Round 6
// 2316.825 us; speedup vs baseline: 1.3034x; 1.3034x over previous
//
#include <hip/hip_runtime.h>

#define HID     1024
#define TSTEPS  19
#define INDIM   17
#define XSTRIDE (TSTEPS * INDIM)

typedef unsigned short u16;
typedef unsigned int   u32;
typedef __attribute__((ext_vector_type(8))) _Float16 f16x8;  // 8 fp16 = 4 VGPRs
typedef __attribute__((ext_vector_type(4))) float f32x4;

__device__ __forceinline__ u16 f2h(float f) {  // fp32 -> fp16 RNE
    union { _Float16 h; u16 u; } v; v.h = (_Float16)f; return v.u;
}
__device__ __forceinline__ float h2f(u16 x) {
    union { _Float16 h; u16 u; } v; v.u = x; return (float)v.h;
}
__device__ __forceinline__ float sigm(float x) {
    x = fminf(fmaxf(x, -30.f), 30.f);
    return 1.f / (1.f + __expf(-x));
}
__device__ __forceinline__ float tanhr(float x) {
    x = fminf(fmaxf(x, -15.f), 15.f);
    float e = __expf(-2.f * x);
    return (1.f - e) / (1.f + e);
}

// Async global->LDS, 16B per lane: HW writes wave-uniform LDS base + lane*16.
__device__ __forceinline__ void gload_lds16(const u16* g, u16* l) {
    __builtin_amdgcn_global_load_lds(
        (const __attribute__((address_space(1))) u32*)g,
        (__attribute__((address_space(3))) u32*)l, 16, 0, 0);
}

// Fused prolog split: fp32 -> fp16 hi for the three big weights + W_lin.
#define NW4 1048576   // float4s per 4H x H weight
__global__ __launch_bounds__(256) void split4_kernel(
    const float* __restrict__ a, u16* __restrict__ ah,
    const float* __restrict__ b, u16* __restrict__ bh,
    const float* __restrict__ c, u16* __restrict__ ch,
    const float* __restrict__ d, u16* __restrict__ dh, int nd4)
{
    int i = blockIdx.x * blockDim.x + threadIdx.x;
    const float* src; u16* dst; int off;
    if (i < NW4)               { src = a; dst = ah; off = i; }
    else if (i < 2 * NW4)      { src = b; dst = bh; off = i - NW4; }
    else if (i < 3 * NW4)      { src = c; dst = ch; off = i - 2 * NW4; }
    else if (i < 3 * NW4 + nd4){ src = d; dst = dh; off = i - 3 * NW4; }
    else return;
    float4 v = ((const float4*)src)[off];
    ushort4 h;
    h.x = f2h(v.x); h.y = f2h(v.y); h.z = f2h(v.z); h.w = f2h(v.w);
    ((ushort4*)dst)[off] = h;
}

// Pre-pack x into standard BK=64 GEMM rows: xpack[(t*4096+b)*64 + k] =
// [xhi(17) | xlo(17) | xhi(17) | 0...] -- the 3-term fp16 split of x[b,t,:]
// as one K=64 stage.
__global__ __launch_bounds__(256) void pack_x_kernel(
    const float* __restrict__ x, u16* __restrict__ xpack)
{
    const int i = blockIdx.x * blockDim.x + threadIdx.x;  // i = t*4096 + b
    if (i >= TSTEPS * 4096) return;
    const int t = i >> 12, b = i & 4095;
    const float* src = x + (size_t)b * XSTRIDE + (size_t)t * INDIM;
    u16 row[64];
#pragma unroll
    for (int k = 0; k < INDIM; ++k) {
        const float v = src[k];
        const u16 hi = f2h(v);
        row[k] = hi;
        row[INDIM + k] = f2h(v - h2f(hi));   // lo
        row[2 * INDIM + k] = hi;
    }
#pragma unroll
    for (int k = 3 * INDIM; k < 64; ++k) row[k] = 0;
    uint4* dst = (uint4*)(xpack + (size_t)i * 64);
#pragma unroll
    for (int q = 0; q < 8; ++q) dst[q] = ((const uint4*)row)[q];
}

// Pre-pack W_ih1 rows to match: wxpack[n*64 + k] = [Whi | Whi | Wlo | 0].
__global__ __launch_bounds__(256) void pack_wx_kernel(
    const float* __restrict__ W, u16* __restrict__ wxpack)
{
    const int n = blockIdx.x * blockDim.x + threadIdx.x;
    if (n >= 4 * HID) return;
    const float* src = W + (size_t)n * INDIM;
    u16 row[64];
#pragma unroll
    for (int k = 0; k < INDIM; ++k) {
        const float v = src[k];
        const u16 hi = f2h(v);
        row[k] = hi;
        row[INDIM + k] = hi;
        row[2 * INDIM + k] = f2h(v - h2f(hi));  // lo
    }
#pragma unroll
    for (int k = 3 * INDIM; k < 64; ++k) row[k] = 0;
    uint4* dst = (uint4*)(wxpack + (size_t)n * 64);
#pragma unroll
    for (int q = 0; q < 8; ++q) dst[q] = ((const uint4*)row)[q];
}

// Fused GEMM + LSTM cell body -- 256x128 tile, 4 waves. r19 = r14's
// VERIFIED structure byte-for-byte (2x __syncthreads/stage, A+B staged
// via gload_lds, 16x16x32 MFMA, 0 bank conflicts), with ONE change kept
// from r17/r18's evidence: the s2-INNER exact-write epilogue (both 64B
// halves of each 128B c-line stored back-to-back -> WRITE_SIZE
// 64.5->49.5MB, the algorithmic minimum).
// Structural deviations REFUTED this session (keep as ledger):
//  - counted-vmcnt/raw-barrier pipeline (r15: spill collapse at the
//    256-reg cap; r16: 3.4x wait inflation -- m232's failed quadrant)
//  - 32x32x16 shape (r17: +9.6M LDS bank conflicts, 4cy/read -- 128B row
//    stride makes the 32-lane column read structurally 4-way)
//  - A direct global->VGPR (r18: exposed ~300cy L2 latency inside the
//    compute phase; the gload_lds A-staging IS the latency hider, and
//    register prefetch doesn't fit under the 256-reg/2-wave cap)
__device__ __forceinline__ void gate_body(
    u16* lA, u16* lB, int rb, int u0,
    const u16* __restrict__ a0, const u16* __restrict__ w0,
    const u16* __restrict__ a1, const u16* __restrict__ w1,
    const u16* __restrict__ xp, const u16* __restrict__ wxp,
    const float* __restrict__ bi, const float* __restrict__ bh,
    float* __restrict__ cbuf, u16* __restrict__ outh,
    int first, int nsrc)
{
    const int tid  = threadIdx.x;
    const int wave = tid >> 6;    // 0..3
    const int lane = tid & 63;
    const int col  = lane & 15;   // MFMA A/B m|n index; C/D col
    const int quad = lane >> 4;   // MFMA k-group; C/D row group

    const int lr = lane >> 3;         // staging row-in-group-of-8
    const int ck = (lane & 7) ^ lr;   // xor-swizzled global chunk to fetch

    f32x4 acc[4][8];
    const f32x4 fzero = {0.f, 0.f, 0.f, 0.f};
#pragma unroll
    for (int i = 0; i < 4; ++i)
#pragma unroll
        for (int j = 0; j < 8; ++j) acc[i][j] = fzero;

    const int nst = nsrc << 4;                  // 16 stages per stride-HID pair
    const int ntot = nst + (xp ? 1 : 0);        // + one packed x stage
    for (int s = 0; s < ntot; ++s) {
        const bool isx = (s >= nst);
        const u16* Asrc = isx ? xp  : ((s < 16) ? a0 : a1);
        const u16* Wsrc = isx ? wxp : ((s < 16) ? w0 : w1);
        const int k0 = isx ? 0 : (s & 15) * 64;
        const int st = isx ? 64 : HID;          // row stride (elements)

        __syncthreads();  // previous stage's (or previous body's) reads done
#pragma unroll
        for (int i = 0; i < 8; ++i) {   // A: rows of this wave's 64-row slab
            const int rbase = wave * 64 + i * 8;
            const int r = rbase + lr;
            const u16* gp = Asrc + (size_t)(rb + r) * st + k0 + ck * 8;
            gload_lds16(gp, lA + rbase * 64);   // lane lands at +lane*16B
        }
#pragma unroll
        for (int i = 0; i < 4; ++i) {   // B: this wave's quarter of 128 rows
            const int vbase = wave * 32 + i * 8;
            const int v = vbase + lr;
            const int n = ((v >> 5) << 10) + u0 + (v & 31);  // gate*1024 + u
            const u16* gp = Wsrc + (size_t)n * st + k0 + ck * 8;
            gload_lds16(gp, lB + vbase * 64);
        }
        __syncthreads();  // staging visible (barrier drains vmcnt)

#pragma unroll
        for (int ks = 0; ks < 2; ++ks) {
            const int p = ((ks << 2) + quad) ^ (col & 7);  // swizzled chunk
            f16x8 av[4], bv[8];
#pragma unroll
            for (int rf = 0; rf < 4; ++rf)
                av[rf] = *(const f16x8*)(lA + (wave * 64 + rf * 16 + col) * 64 + p * 8);
#pragma unroll
            for (int cf = 0; cf < 8; ++cf)
                bv[cf] = *(const f16x8*)(lB + (cf * 16 + col) * 64 + p * 8);
#pragma unroll
            for (int rf = 0; rf < 4; ++rf)
#pragma unroll
                for (int cf = 0; cf < 8; ++cf)
                    acc[rf][cf] = __builtin_amdgcn_mfma_f32_16x16x32_f16(
                        av[rf], bv[cf], acc[rf][cf], 0, 0, 0);
        }
    }

    // Epilogue: per-lane LSTM cell. C/D layout: col=lane&15, row=quad*4+reg.
    // Gates of unit u = u0 + s2*16 + col live at cf = {s2, 2+s2, 4+s2, 6+s2}.
    // s2-INNER: the two 64B halves of each 128B c-line (and the two 32B
    // halves of each 64B h chunk) store back-to-back -> full-line writeback.
    // Evidence r17/r18: WRITE_SIZE drops to the 49.5MB algorithmic minimum
    // (r14's s2-outer split cost +15MB partial-line RMW).
    const int u_a = u0 + col;         // s2 = 0
    const int u_b = u0 + 16 + col;    // s2 = 1
    const float bIa = bi[u_a]           + bh[u_a];
    const float bFa = bi[HID + u_a]     + bh[HID + u_a];
    const float bGa = bi[2 * HID + u_a] + bh[2 * HID + u_a];
    const float bOa = bi[3 * HID + u_a] + bh[3 * HID + u_a];
    const float bIb = bi[u_b]           + bh[u_b];
    const float bFb = bi[HID + u_b]     + bh[HID + u_b];
    const float bGb = bi[2 * HID + u_b] + bh[2 * HID + u_b];
    const float bOb = bi[3 * HID + u_b] + bh[3 * HID + u_b];
#pragma unroll
    for (int rf = 0; rf < 4; ++rf) {
#pragma unroll
        for (int rr = 0; rr < 4; ++rr) {
            const int brow = rb + wave * 64 + rf * 16 + quad * 4 + rr;
            const size_t idx0 = (size_t)brow * HID + u_a;
            const size_t idx1 = idx0 + 16;
            const float iva = sigm(acc[rf][0][rr] + bIa);
            const float fva = sigm(acc[rf][2][rr] + bFa);
            const float gva = tanhr(acc[rf][4][rr] + bGa);
            const float ova = sigm(acc[rf][6][rr] + bOa);
            const float ivb = sigm(acc[rf][1][rr] + bIb);
            const float fvb = sigm(acc[rf][3][rr] + bFb);
            const float gvb = tanhr(acc[rf][5][rr] + bGb);
            const float ovb = sigm(acc[rf][7][rr] + bOb);
            const float colda = first ? 0.f : cbuf[idx0];
            const float coldb = first ? 0.f : cbuf[idx1];
            const float cna = fva * colda + iva * gva;
            const float cnb = fvb * coldb + ivb * gvb;
            const float hna = ova * tanhr(cna);
            const float hnb = ovb * tanhr(cnb);
            cbuf[idx0] = cna;
            cbuf[idx1] = cnb;
            outh[idx0] = f2h(hna);
            outh[idx1] = f2h(hnb);
        }
    }
}

// out[b, t, :] = h2[b,:] @ W_lin^T + b_lin (h2 fp16, W_lin pre-split fp16).
__device__ __forceinline__ void out_body8(int oid,
    const u16* __restrict__ h2h,
    const u16* __restrict__ Wlin, const float* __restrict__ blin,
    float* __restrict__ out, int t)
{
    const int tid = threadIdx.x;
    const int wave = tid >> 6, lane = tid & 63;
    const int r = lane >> 5, q = lane & 31;
    const int b = oid * 8 + wave * 2 + r;
    const u16* hh = h2h + (size_t)b * HID;
    float acc[INDIM];
#pragma unroll
    for (int j = 0; j < INDIM; ++j) acc[j] = 0.f;
#pragma unroll 2
    for (int it = 0; it < 8; ++it) {
        const int u = q * 32 + it * 4;
        const ushort4 a = *(const ushort4*)(hh + u);
        const float h0 = h2f(a.x), h1 = h2f(a.y), h2 = h2f(a.z), h3 = h2f(a.w);
#pragma unroll
        for (int j = 0; j < INDIM; ++j) {
            const ushort4 w = *(const ushort4*)(Wlin + j * HID + u);
            acc[j] += h0 * h2f(w.x) + h1 * h2f(w.y)
                    + h2 * h2f(w.z) + h3 * h2f(w.w);
        }
    }
#pragma unroll
    for (int j = 0; j < INDIM; ++j) {   // reduce across the 32 q-slices
        float v = acc[j];
        v += __shfl_xor(v, 1);
        v += __shfl_xor(v, 2);
        v += __shfl_xor(v, 4);
        v += __shfl_xor(v, 8);
        v += __shfl_xor(v, 16);
        acc[j] = v;
    }
    const size_t ob = (size_t)b * XSTRIDE + (size_t)t * INDIM;
    float mine = acc[0];
#pragma unroll
    for (int j = 1; j < INDIM; ++j) if (q == j) mine = acc[j];
    if (q < INDIM) out[ob + q] = mine + blin[q];
}

// Fused pipeline step C(s) = { L2(s-1) + L1(s) + OUT(s-2) }, grid EXACTLY
// 512 blocks x 256 thr (2 blocks/CU at 48KB LDS -> 1.0 scheduling rounds).
// Role-order STAGGER by block parity (r14, +2%): odd blocks run B first,
// even blocks A first -> a CU's two resident blocks are mostly in different
// roles; MFMA windows overlap the neighbor's staging/barrier drains (m114).
// XCD-pinned u0 (perf heuristic only). Buffer schedule = verified 4-deep
// slab rotation (r8/r10/r11/r12/r14).
__global__ __launch_bounds__(256, 2) void step_kernel(
    int doA, int doB,
    // role A: layer 2 of step s-1
    const u16* __restrict__ Aa0, const u16* __restrict__ Aw0,
    const u16* __restrict__ Aa1, const u16* __restrict__ Aw1,
    const float* __restrict__ Abi, const float* __restrict__ Abh,
    float* __restrict__ Acbuf, u16* __restrict__ Aouth, int Afirst, int Ansrc,
    // role B: layer 1 of step s (x via pre-packed stride-64 pair)
    const u16* __restrict__ Ba0, const u16* __restrict__ Bw0,
    const u16* __restrict__ Bxp, const u16* __restrict__ Bwxp,
    const float* __restrict__ Bbi, const float* __restrict__ Bbh,
    float* __restrict__ Bcbuf, u16* __restrict__ Bouth, int Bfirst, int Bnsrc,
    // role O: output linear of step s-2 (Ot < 0 => skip)
    const u16* __restrict__ Oh2, const u16* __restrict__ Wlin,
    const float* __restrict__ blin, float* __restrict__ outp, int Ot)
{
    __shared__ u16 lA[256 * 64];   // 32 KB: 256 batch rows x BK=64
    __shared__ u16 lB[128 * 64];   // 16 KB: 128 weight rows x BK=64
    const int bid = blockIdx.x;
    const int rb  = (bid >> 5) * 256;                        // batch-row block
    const int u0  = ((bid & 7) * 4 + ((bid >> 3) & 3)) * 32; // XCD-pinned tile
    const auto runA = [&]() {
        gate_body(lA, lB, rb, u0, Aa0, Aw0, Aa1, Aw1, nullptr, nullptr,
                  Abi, Abh, Acbuf, Aouth, Afirst, Ansrc);
    };
    const auto runB = [&]() {
        gate_body(lA, lB, rb, u0, Ba0, Bw0, nullptr, nullptr, Bxp, Bwxp,
                  Bbi, Bbh, Bcbuf, Bouth, Bfirst, Bnsrc);
    };
    if (bid & 1) { if (doB) runB(); if (doA) runA(); }
    else         { if (doA) runA(); if (doB) runB(); }
    if (Ot >= 0)
        out_body8(bid, Oh2, Wlin, blin, outp, Ot);
}

extern "C" void kernel_launch(void* const* d_in, const int* in_sizes, int n_in,
                              void* d_out, int out_size, void* d_ws, size_t ws_size,
                              hipStream_t stream)
{
    const float* x     = (const float*)d_in[0];
    const float* W_ih1 = (const float*)d_in[1];
    const float* W_hh1 = (const float*)d_in[2];
    const float* b_ih1 = (const float*)d_in[3];
    const float* b_hh1 = (const float*)d_in[4];
    const float* W_ih2 = (const float*)d_in[5];
    const float* W_hh2 = (const float*)d_in[6];
    const float* b_ih2 = (const float*)d_in[7];
    const float* b_hh2 = (const float*)d_in[8];
    const float* W_lin = (const float*)d_in[9];
    const float* b_lin = (const float*)d_in[10];
    float* out = (float*)d_out;
    char* ws = (char*)d_ws;
    const size_t MB = (size_t)1 << 20;

    // Workspace (~132 MB; no memset -- first=1 skips all reads of
    // uninitialized state at t=0). c1/c2 fp32; h1/h2: FOUR 8MB fp16 slabs
    // each (t&3); wlin16 = fp16 W_lin for the O-body.
    float* c1 = (float*)(ws);             // 16 MB (4096x1024 fp32)
    float* c2 = (float*)(ws + 16 * MB);   // 16 MB
    u16* h1[4] = { (u16*)(ws + 32 * MB), (u16*)(ws + 40 * MB),
                   (u16*)(ws + 48 * MB), (u16*)(ws + 56 * MB) };
    u16* h2[4] = { (u16*)(ws + 64 * MB), (u16*)(ws + 72 * MB),
                   (u16*)(ws + 80 * MB), (u16*)(ws + 88 * MB) };
    u16* w1h    = (u16*)(ws + 96 * MB);   // 8 MB each (4H x H fp16)
    u16* w2ih   = (u16*)(ws + 104 * MB);
    u16* w2hh   = (u16*)(ws + 112 * MB);
    u16* xpack  = (u16*)(ws + 120 * MB);  // 19*4096*64 fp16 = 9.97 MB
    u16* wxpack = (u16*)(ws + 130 * MB);  // 4096*64 fp16 = 0.5 MB
    u16* wlin16 = (u16*)(ws + 131 * MB);  // 17*1024 fp16 = 34 KB

    // Prolog (3 launches): fused weight+W_lin fp16 splits, x / W_ih1 packs.
    const int nWlin4 = INDIM * HID / 4;   // 4352 float4s
    const int nTot = 3 * NW4 + nWlin4;
    split4_kernel<<<(nTot + 255) / 256, 256, 0, stream>>>(
        W_hh1, w1h, W_ih2, w2ih, W_hh2, w2hh, W_lin, wlin16, nWlin4);
    pack_x_kernel<<<(TSTEPS * 4096 + 255) / 256, 256, 0, stream>>>(x, xpack);
    pack_wx_kernel<<<(4 * HID + 255) / 256, 256, 0, stream>>>(W_ih1, wxpack);

    // Software pipeline: C(s) = { L2(s-1) + L1(s) + OUT(s-2) }, s=0..TSTEPS+1.
    // Slabs: L1(t) reads h1[(t+3)&3], writes h1[t&3]; L2(t) reads h1[t&3],
    // h2[(t+3)&3], writes h2[t&3]; OUT(t) reads h2[t&3]. Intra-launch sets
    // disjoint; RAW >= 1 launch, WAR >= 3 launches (verified r8-r14).
    for (int s = 0; s <= TSTEPS + 1; ++s) {
        const int ta = s - 1, tb = s, to = s - 2;
        const int doA = (s >= 1 && s <= TSTEPS) ? 1 : 0;
        const int doB = (s <= TSTEPS - 1) ? 1 : 0;
        step_kernel<<<512, 256, 0, stream>>>(
            doA, doB,
            // A: L2(ta) = h1[ta&3]@w2ih + h2[(ta+3)&3]@w2hh -> h2[ta&3]
            h1[ta & 3], w2ih, h2[(ta + 3) & 3], w2hh, b_ih2, b_hh2,
            c2, h2[ta & 3], (ta == 0) ? 1 : 0, (ta == 0) ? 1 : 2,
            // B: L1(tb) = xpack(tb) + h1[(tb+3)&3]@w1h -> h1[tb&3]
            h1[(tb + 3) & 3], w1h,
            xpack + (size_t)(tb < 0 ? 0 : tb) * 4096 * 64, wxpack,
            b_ih1, b_hh1,
            c1, h1[tb & 3], (tb == 0) ? 1 : 0, (tb == 0) ? 0 : 1,
            // O: OUT(to) reads h2[to&3] (skipped when to < 0)
            h2[to & 3], wlin16, b_lin, out, to);
    }
    (void)in_sizes; (void)n_in; (void)out_size; (void)ws_size;
}

// Round 7
// 2272.734 us; speedup vs baseline: 1.3287x; 1.0194x over previous
//
#include <hip/hip_runtime.h>

#define HID     1024
#define TSTEPS  19
#define INDIM   17
#define XSTRIDE (TSTEPS * INDIM)

typedef unsigned short u16;
typedef unsigned int   u32;
typedef __attribute__((ext_vector_type(8))) _Float16 f16x8;  // 8 fp16 = 4 VGPRs
typedef __attribute__((ext_vector_type(4))) float f32x4;

__device__ __forceinline__ u16 f2h(float f) {  // fp32 -> fp16 RNE
    union { _Float16 h; u16 u; } v; v.h = (_Float16)f; return v.u;
}
__device__ __forceinline__ float h2f(u16 x) {
    union { _Float16 h; u16 u; } v; v.u = x; return (float)v.h;
}
__device__ __forceinline__ float sigm(float x) {
    x = fminf(fmaxf(x, -30.f), 30.f);
    return 1.f / (1.f + __expf(-x));
}
__device__ __forceinline__ float tanhr(float x) {
    x = fminf(fmaxf(x, -15.f), 15.f);
    float e = __expf(-2.f * x);
    return (1.f - e) / (1.f + e);
}

// Async global->LDS, 16B per lane: HW writes wave-uniform LDS base + lane*16.
__device__ __forceinline__ void gload_lds16(const u16* g, u16* l) {
    __builtin_amdgcn_global_load_lds(
        (const __attribute__((address_space(1))) u32*)g,
        (__attribute__((address_space(3))) u32*)l, 16, 0, 0);
}

// Fused prolog split: fp32 -> fp16 hi for the three big weights + W_lin.
#define NW4 1048576   // float4s per 4H x H weight
__global__ __launch_bounds__(256) void split4_kernel(
    const float* __restrict__ a, u16* __restrict__ ah,
    const float* __restrict__ b, u16* __restrict__ bh,
    const float* __restrict__ c, u16* __restrict__ ch,
    const float* __restrict__ d, u16* __restrict__ dh, int nd4)
{
    int i = blockIdx.x * blockDim.x + threadIdx.x;
    const float* src; u16* dst; int off;
    if (i < NW4)               { src = a; dst = ah; off = i; }
    else if (i < 2 * NW4)      { src = b; dst = bh; off = i - NW4; }
    else if (i < 3 * NW4)      { src = c; dst = ch; off = i - 2 * NW4; }
    else if (i < 3 * NW4 + nd4){ src = d; dst = dh; off = i - 3 * NW4; }
    else return;
    float4 v = ((const float4*)src)[off];
    ushort4 h;
    h.x = f2h(v.x); h.y = f2h(v.y); h.z = f2h(v.z); h.w = f2h(v.w);
    ((ushort4*)dst)[off] = h;
}

// Pre-pack x into standard BK=64 GEMM rows: xpack[(t*4096+b)*64 + k] =
// [xhi(17) | xlo(17) | xhi(17) | 0...] -- the 3-term fp16 split of x[b,t,:]
// as one K=64 stage.
__global__ __launch_bounds__(256) void pack_x_kernel(
    const float* __restrict__ x, u16* __restrict__ xpack)
{
    const int i = blockIdx.x * blockDim.x + threadIdx.x;  // i = t*4096 + b
    if (i >= TSTEPS * 4096) return;
    const int t = i >> 12, b = i & 4095;
    const float* src = x + (size_t)b * XSTRIDE + (size_t)t * INDIM;
    u16 row[64];
#pragma unroll
    for (int k = 0; k < INDIM; ++k) {
        const float v = src[k];
        const u16 hi = f2h(v);
        row[k] = hi;
        row[INDIM + k] = f2h(v - h2f(hi));   // lo
        row[2 * INDIM + k] = hi;
    }
#pragma unroll
    for (int k = 3 * INDIM; k < 64; ++k) row[k] = 0;
    uint4* dst = (uint4*)(xpack + (size_t)i * 64);
#pragma unroll
    for (int q = 0; q < 8; ++q) dst[q] = ((const uint4*)row)[q];
}

// Pre-pack W_ih1 rows to match: wxpack[n*64 + k] = [Whi | Whi | Wlo | 0].
__global__ __launch_bounds__(256) void pack_wx_kernel(
    const float* __restrict__ W, u16* __restrict__ wxpack)
{
    const int n = blockIdx.x * blockDim.x + threadIdx.x;
    if (n >= 4 * HID) return;
    const float* src = W + (size_t)n * INDIM;
    u16 row[64];
#pragma unroll
    for (int k = 0; k < INDIM; ++k) {
        const float v = src[k];
        const u16 hi = f2h(v);
        row[k] = hi;
        row[INDIM + k] = hi;
        row[2 * INDIM + k] = f2h(v - h2f(hi));  // lo
    }
#pragma unroll
    for (int k = 3 * INDIM; k < 64; ++k) row[k] = 0;
    uint4* dst = (uint4*)(wxpack + (size_t)n * 64);
#pragma unroll
    for (int q = 0; q < 8; ++q) dst[q] = ((const uint4*)row)[q];
}

// r20: AFFINE stage sub-loop (loop fission of r19's select-loop).
// Same verified 2-barrier structure, staging pattern, LDS layout and MFMA
// as r14/r19 -- but source pointers / stride are loop-constant (ST is a
// template arg), so the per-lane address collapses to ONE loop-invariant
// u32 offset + a uniform pointer advancing 64 elements/stage. This removes
// the per-stage 64-bit address chains + source selects (~120 VALU
// instrs/wave/stage) that r19's VALUBusy=40% was paying for.
//   A load i: As + aoff0 + i*8*ST, aoff0 = (rb+wave*64+lr)*ST + ck*8
//   B load i: Ws + boff0 + i*8*ST, boff0 = (wave*1024+u0+lr)*ST + ck*8
//     (B row n = ((v>>5)<<10)+u0+(v&31) with v=wave*32+i*8+lr is LINEAR in
//      i because v>>5==wave for all i: n = wave*1024+u0+i*8+lr.)
template<int ST>
__device__ __forceinline__ void stage_loop(
    u16* lA, u16* lB, int nstages,
    const u16* As, const u16* Ws,
    int aoff0, int boff0, int wave, int col, int quad,
    f32x4 (&acc)[4][8])
{
    for (int s = 0; s < nstages; ++s) {
        __syncthreads();  // previous stage's (or previous body's) reads done
#pragma unroll
        for (int i = 0; i < 8; ++i)   // A: rows of this wave's 64-row slab
            gload_lds16(As + aoff0 + i * 8 * ST, lA + (wave * 64 + i * 8) * 64);
#pragma unroll
        for (int i = 0; i < 4; ++i)   // B: this wave's quarter of 128 rows
            gload_lds16(Ws + boff0 + i * 8 * ST, lB + (wave * 32 + i * 8) * 64);
        __syncthreads();  // staging visible (barrier drains vmcnt)

#pragma unroll
        for (int ks = 0; ks < 2; ++ks) {
            const int p = ((ks << 2) + quad) ^ (col & 7);  // swizzled chunk
            f16x8 av[4], bv[8];
#pragma unroll
            for (int rf = 0; rf < 4; ++rf)
                av[rf] = *(const f16x8*)(lA + (wave * 64 + rf * 16 + col) * 64 + p * 8);
#pragma unroll
            for (int cf = 0; cf < 8; ++cf)
                bv[cf] = *(const f16x8*)(lB + (cf * 16 + col) * 64 + p * 8);
#pragma unroll
            for (int rf = 0; rf < 4; ++rf)
#pragma unroll
                for (int cf = 0; cf < 8; ++cf)
                    acc[rf][cf] = __builtin_amdgcn_mfma_f32_16x16x32_f16(
                        av[rf], bv[cf], acc[rf][cf], 0, 0, 0);
        }
        As += 64; Ws += 64;   // k0 advance: uniform pointer bump, no re-derive
    }
}

// Fused GEMM + LSTM cell body -- 256x128 tile, 4 waves. r20 = r19's
// verified structure (2x __syncthreads/stage, A+B via gload_lds, 16x16x32
// MFMA, 0 conflicts, s2-inner exact-write epilogue = 49.5MB WRITE minimum)
// with the stage loop FISSIONED into affine sub-loops (see stage_loop).
// Session ledger of refuted deviations: counted-vmcnt pipeline (r15 spill /
// r16 wait-inflation), 32x32x16 shape (r17 +9.6M bank conflicts), A-direct
// global->VGPR (r18 exposed L2 latency in the compute phase).
__device__ __forceinline__ void gate_body(
    u16* lA, u16* lB, int rb, int u0,
    const u16* __restrict__ a0, const u16* __restrict__ w0,
    const u16* __restrict__ a1, const u16* __restrict__ w1,
    const u16* __restrict__ xp, const u16* __restrict__ wxp,
    const float* __restrict__ bi, const float* __restrict__ bh,
    float* __restrict__ cbuf, u16* __restrict__ outh,
    int first, int nsrc)
{
    const int tid  = threadIdx.x;
    const int wave = tid >> 6;    // 0..3
    const int lane = tid & 63;
    const int col  = lane & 15;   // MFMA A/B m|n index; C/D col
    const int quad = lane >> 4;   // MFMA k-group; C/D row group

    const int lr = lane >> 3;         // staging row-in-group-of-8
    const int ck = (lane & 7) ^ lr;   // xor-swizzled global chunk to fetch

    f32x4 acc[4][8];
    const f32x4 fzero = {0.f, 0.f, 0.f, 0.f};
#pragma unroll
    for (int i = 0; i < 4; ++i)
#pragma unroll
        for (int j = 0; j < 8; ++j) acc[i][j] = fzero;

    // Loop-invariant per-lane offsets (elements), one per stride.
    const int arow = rb + wave * 64 + lr;
    const int brow = wave * 1024 + u0 + lr;
    const int aoffH = arow * HID + ck * 8;
    const int boffH = brow * HID + ck * 8;

    if (nsrc >= 1)
        stage_loop<HID>(lA, lB, 16, a0, w0, aoffH, boffH, wave, col, quad, acc);
    if (nsrc >= 2)
        stage_loop<HID>(lA, lB, 16, a1, w1, aoffH, boffH, wave, col, quad, acc);
    if (xp) {
        const int aoffX = arow * 64 + ck * 8;
        const int boffX = brow * 64 + ck * 8;
        stage_loop<64>(lA, lB, 1, xp, wxp, aoffX, boffX, wave, col, quad, acc);
    }

    // Epilogue: per-lane LSTM cell. C/D layout: col=lane&15, row=quad*4+reg.
    // Gates of unit u = u0 + s2*16 + col live at cf = {s2, 2+s2, 4+s2, 6+s2}.
    // s2-INNER: both 64B halves of each 128B c-line stored back-to-back ->
    // full-line writeback (r17/r18/r19 evidence: WRITE_SIZE at the 49.5MB
    // algorithmic minimum vs r14's +15MB partial-line RMW).
    const int u_a = u0 + col;         // s2 = 0
    const int u_b = u0 + 16 + col;    // s2 = 1
    const float bIa = bi[u_a]           + bh[u_a];
    const float bFa = bi[HID + u_a]     + bh[HID + u_a];
    const float bGa = bi[2 * HID + u_a] + bh[2 * HID + u_a];
    const float bOa = bi[3 * HID + u_a] + bh[3 * HID + u_a];
    const float bIb = bi[u_b]           + bh[u_b];
    const float bFb = bi[HID + u_b]     + bh[HID + u_b];
    const float bGb = bi[2 * HID + u_b] + bh[2 * HID + u_b];
    const float bOb = bi[3 * HID + u_b] + bh[3 * HID + u_b];
#pragma unroll
    for (int rf = 0; rf < 4; ++rf) {
#pragma unroll
        for (int rr = 0; rr < 4; ++rr) {
            const int brw = rb + wave * 64 + rf * 16 + quad * 4 + rr;
            const size_t idx0 = (size_t)brw * HID + u_a;
            const size_t idx1 = idx0 + 16;
            const float iva = sigm(acc[rf][0][rr] + bIa);
            const float fva = sigm(acc[rf][2][rr] + bFa);
            const float gva = tanhr(acc[rf][4][rr] + bGa);
            const float ova = sigm(acc[rf][6][rr] + bOa);
            const float ivb = sigm(acc[rf][1][rr] + bIb);
            const float fvb = sigm(acc[rf][3][rr] + bFb);
            const float gvb = tanhr(acc[rf][5][rr] + bGb);
            const float ovb = sigm(acc[rf][7][rr] + bOb);
            const float colda = first ? 0.f : cbuf[idx0];
            const float coldb = first ? 0.f : cbuf[idx1];
            const float cna = fva * colda + iva * gva;
            const float cnb = fvb * coldb + ivb * gvb;
            const float hna = ova * tanhr(cna);
            const float hnb = ovb * tanhr(cnb);
            cbuf[idx0] = cna;
            cbuf[idx1] = cnb;
            outh[idx0] = f2h(hna);
            outh[idx1] = f2h(hnb);
        }
    }
}

// out[b, t, :] = h2[b,:] @ W_lin^T + b_lin (h2 fp16, W_lin pre-split fp16).
__device__ __forceinline__ void out_body8(int oid,
    const u16* __restrict__ h2h,
    const u16* __restrict__ Wlin, const float* __restrict__ blin,
    float* __restrict__ out, int t)
{
    const int tid = threadIdx.x;
    const int wave = tid >> 6, lane = tid & 63;
    const int r = lane >> 5, q = lane & 31;
    const int b = oid * 8 + wave * 2 + r;
    const u16* hh = h2h + (size_t)b * HID;
    float acc[INDIM];
#pragma unroll
    for (int j = 0; j < INDIM; ++j) acc[j] = 0.f;
#pragma unroll 2
    for (int it = 0; it < 8; ++it) {
        const int u = q * 32 + it * 4;
        const ushort4 a = *(const ushort4*)(hh + u);
        const float h0 = h2f(a.x), h1 = h2f(a.y), h2 = h2f(a.z), h3 = h2f(a.w);
#pragma unroll
        for (int j = 0; j < INDIM; ++j) {
            const ushort4 w = *(const ushort4*)(Wlin + j * HID + u);
            acc[j] += h0 * h2f(w.x) + h1 * h2f(w.y)
                    + h2 * h2f(w.z) + h3 * h2f(w.w);
        }
    }
#pragma unroll
    for (int j = 0; j < INDIM; ++j) {   // reduce across the 32 q-slices
        float v = acc[j];
        v += __shfl_xor(v, 1);
        v += __shfl_xor(v, 2);
        v += __shfl_xor(v, 4);
        v += __shfl_xor(v, 8);
        v += __shfl_xor(v, 16);
        acc[j] = v;
    }
    const size_t ob = (size_t)b * XSTRIDE + (size_t)t * INDIM;
    float mine = acc[0];
#pragma unroll
    for (int j = 1; j < INDIM; ++j) if (q == j) mine = acc[j];
    if (q < INDIM) out[ob + q] = mine + blin[q];
}

// Fused pipeline step C(s) = { L2(s-1) + L1(s) + OUT(s-2) }, grid EXACTLY
// 512 blocks x 256 thr (2 blocks/CU at 48KB LDS -> 1.0 scheduling rounds).
// Role-order STAGGER by block parity (r14, +2%): odd blocks run B first,
// even blocks A first -> a CU's two resident blocks are mostly in different
// roles; MFMA windows overlap the neighbor's staging/barrier drains (m114).
// XCD-pinned u0 (perf heuristic only). Buffer schedule = verified 4-deep
// slab rotation (r8/r10/r11/r12/r14).
__global__ __launch_bounds__(256, 2) void step_kernel(
    int doA, int doB,
    // role A: layer 2 of step s-1
    const u16* __restrict__ Aa0, const u16* __restrict__ Aw0,
    const u16* __restrict__ Aa1, const u16* __restrict__ Aw1,
    const float* __restrict__ Abi, const float* __restrict__ Abh,
    float* __restrict__ Acbuf, u16* __restrict__ Aouth, int Afirst, int Ansrc,
    // role B: layer 1 of step s (x via pre-packed stride-64 pair)
    const u16* __restrict__ Ba0, const u16* __restrict__ Bw0,
    const u16* __restrict__ Bxp, const u16* __restrict__ Bwxp,
    const float* __restrict__ Bbi, const float* __restrict__ Bbh,
    float* __restrict__ Bcbuf, u16* __restrict__ Bouth, int Bfirst, int Bnsrc,
    // role O: output linear of step s-2 (Ot < 0 => skip)
    const u16* __restrict__ Oh2, const u16* __restrict__ Wlin,
    const float* __restrict__ blin, float* __restrict__ outp, int Ot)
{
    __shared__ u16 lA[256 * 64];   // 32 KB: 256 batch rows x BK=64
    __shared__ u16 lB[128 * 64];   // 16 KB: 128 weight rows x BK=64
    const int bid = blockIdx.x;
    const int rb  = (bid >> 5) * 256;                        // batch-row block
    const int u0  = ((bid & 7) * 4 + ((bid >> 3) & 3)) * 32; // XCD-pinned tile
    const auto runA = [&]() {
        gate_body(lA, lB, rb, u0, Aa0, Aw0, Aa1, Aw1, nullptr, nullptr,
                  Abi, Abh, Acbuf, Aouth, Afirst, Ansrc);
    };
    const auto runB = [&]() {
        gate_body(lA, lB, rb, u0, Ba0, Bw0, nullptr, nullptr, Bxp, Bwxp,
                  Bbi, Bbh, Bcbuf, Bouth, Bfirst, Bnsrc);
    };
    if (bid & 1) { if (doB) runB(); if (doA) runA(); }
    else         { if (doA) runA(); if (doB) runB(); }
    if (Ot >= 0)
        out_body8(bid, Oh2, Wlin, blin, outp, Ot);
}

extern "C" void kernel_launch(void* const* d_in, const int* in_sizes, int n_in,
                              void* d_out, int out_size, void* d_ws, size_t ws_size,
                              hipStream_t stream)
{
    const float* x     = (const float*)d_in[0];
    const float* W_ih1 = (const float*)d_in[1];
    const float* W_hh1 = (const float*)d_in[2];
    const float* b_ih1 = (const float*)d_in[3];
    const float* b_hh1 = (const float*)d_in[4];
    const float* W_ih2 = (const float*)d_in[5];
    const float* W_hh2 = (const float*)d_in[6];
    const float* b_ih2 = (const float*)d_in[7];
    const float* b_hh2 = (const float*)d_in[8];
    const float* W_lin = (const float*)d_in[9];
    const float* b_lin = (const float*)d_in[10];
    float* out = (float*)d_out;
    char* ws = (char*)d_ws;
    const size_t MB = (size_t)1 << 20;

    // Workspace (~132 MB; no memset -- first=1 skips all reads of
    // uninitialized state at t=0). c1/c2 fp32; h1/h2: FOUR 8MB fp16 slabs
    // each (t&3); wlin16 = fp16 W_lin for the O-body.
    float* c1 = (float*)(ws);             // 16 MB (4096x1024 fp32)
    float* c2 = (float*)(ws + 16 * MB);   // 16 MB
    u16* h1[4] = { (u16*)(ws + 32 * MB), (u16*)(ws + 40 * MB),
                   (u16*)(ws + 48 * MB), (u16*)(ws + 56 * MB) };
    u16* h2[4] = { (u16*)(ws + 64 * MB), (u16*)(ws + 72 * MB),
                   (u16*)(ws + 80 * MB), (u16*)(ws + 88 * MB) };
    u16* w1h    = (u16*)(ws + 96 * MB);   // 8 MB each (4H x H fp16)
    u16* w2ih   = (u16*)(ws + 104 * MB);
    u16* w2hh   = (u16*)(ws + 112 * MB);
    u16* xpack  = (u16*)(ws + 120 * MB);  // 19*4096*64 fp16 = 9.97 MB
    u16* wxpack = (u16*)(ws + 130 * MB);  // 4096*64 fp16 = 0.5 MB
    u16* wlin16 = (u16*)(ws + 131 * MB);  // 17*1024 fp16 = 34 KB

    // Prolog (3 launches): fused weight+W_lin fp16 splits, x / W_ih1 packs.
    const int nWlin4 = INDIM * HID / 4;   // 4352 float4s
    const int nTot = 3 * NW4 + nWlin4;
    split4_kernel<<<(nTot + 255) / 256, 256, 0, stream>>>(
        W_hh1, w1h, W_ih2, w2ih, W_hh2, w2hh, W_lin, wlin16, nWlin4);
    pack_x_kernel<<<(TSTEPS * 4096 + 255) / 256, 256, 0, stream>>>(x, xpack);
    pack_wx_kernel<<<(4 * HID + 255) / 256, 256, 0, stream>>>(W_ih1, wxpack);

    // Software pipeline: C(s) = { L2(s-1) + L1(s) + OUT(s-2) }, s=0..TSTEPS+1.
    // Slabs: L1(t) reads h1[(t+3)&3], writes h1[t&3]; L2(t) reads h1[t&3],
    // h2[(t+3)&3], writes h2[t&3]; OUT(t) reads h2[t&3]. Intra-launch sets
    // disjoint; RAW >= 1 launch, WAR >= 3 launches (verified r8-r14).
    for (int s = 0; s <= TSTEPS + 1; ++s) {
        const int ta = s - 1, tb = s, to = s - 2;
        const int doA = (s >= 1 && s <= TSTEPS) ? 1 : 0;
        const int doB = (s <= TSTEPS - 1) ? 1 : 0;
        step_kernel<<<512, 256, 0, stream>>>(
            doA, doB,
            // A: L2(ta) = h1[ta&3]@w2ih + h2[(ta+3)&3]@w2hh -> h2[ta&3]
            h1[ta & 3], w2ih, h2[(ta + 3) & 3], w2hh, b_ih2, b_hh2,
            c2, h2[ta & 3], (ta == 0) ? 1 : 0, (ta == 0) ? 1 : 2,
            // B: L1(tb) = xpack(tb) + h1[(tb+3)&3]@w1h -> h1[tb&3]
            h1[(tb + 3) & 3], w1h,
            xpack + (size_t)(tb < 0 ? 0 : tb) * 4096 * 64, wxpack,
            b_ih1, b_hh1,
            c1, h1[tb & 3], (tb == 0) ? 1 : 0, (tb == 0) ? 0 : 1,
            // O: OUT(to) reads h2[to&3] (skipped when to < 0)
            h2[to & 3], wlin16, b_lin, out, to);
    }
    (void)in_sizes; (void)n_in; (void)out_size; (void)ws_size;
}